// Round 1
// 338.032 us; speedup vs baseline: 1.0636x; 1.0636x over previous
//
#include <hip/hip_runtime.h>
#include <cstdint>

// Problem constants
#define NB 32
#define IC 256
#define OC 256
#define H 56
#define WIDTH 56
#define OH 54
#define OW 54
#define HW (H*WIDTH)          // 3136
#define OHW (OH*OW)           // 2916
#define KTOT 2304             // 9 * 256, k = (kh*3+kw)*256 + c
#define M_TOT (NB*OHW)        // 93312
#define C8N (IC/8)            // 32 chunks of 8 channels

// GEMM tiling
#define BM 128                // spatial tile
#define BO 256                // out-channel tile (= all of OC: X staged once)
#define BK 32
#define KSTEPS (KTOT/BK)      // 72
#define MBLOCKS (M_TOT/BM)    // 729

// weights pre-tiled as per-K-step LDS images WITH chunk swizzle:
// g_qwt[step][r][cs][b] = sign(W[o=r][k = step*32 + (cs ^ ((r>>1)&3))*8 + b])
__device__ __align__(16) unsigned short g_qwt[KSTEPS*BO*BK];
// x as [n][c8][hw][8] bf16 (16B granule = 8 consecutive channels at one pixel)
__device__ __align__(16) unsigned short g_xq[NB*C8N*HW*8];

typedef __bf16 bf16x8 __attribute__((ext_vector_type(8)));
typedef float  f32x4  __attribute__((ext_vector_type(4)));

typedef __attribute__((address_space(1))) const unsigned int gas_u32;
typedef __attribute__((address_space(3))) unsigned int las_u32;
__device__ __forceinline__ void async_copy16(const void* g, void* l) {
  // global -> LDS direct copy, 16 B per lane; LDS dst = wave-uniform base + lane*16
  __builtin_amdgcn_global_load_lds((gas_u32*)g, (las_u32*)l, 16, 0, 0);
}

__device__ inline unsigned short f32_bf16(float f) {
  union { float f; unsigned int u; } v; v.f = f;
  unsigned int u = v.u;
  return (unsigned short)((u + 0x7FFFu + ((u >> 16) & 1u)) >> 16);  // RNE
}

// ---- Kernel 1: binarize + pre-tile weights (swizzled LDS image) ----------
// Iterate destination slot, gather source: writes coalesced, reads L2-cached.
__global__ __launch_bounds__(256) void repack_w(const float* __restrict__ w) {
  int L = blockIdx.x * 256 + threadIdx.x;           // < 589824
  int step = L >> 13;                               // /8192 (256 rows * 32 k)
  int r    = (L >> 5) & 255;
  int kc   = L & 31;
  int cs   = kc >> 3;                               // chunk slot 0..3
  int b    = kc & 7;
  int csrc = cs ^ ((r >> 1) & 3);                   // bank-conflict swizzle
  int k    = step*BK + csrc*8 + b;
  int pos  = k >> 8;                                // kh*3+kw
  int c    = k & 255;
  float v = w[r*2304 + c*9 + pos];
  unsigned short s = (v > 0.f) ? 0x3F80u : ((v < 0.f) ? 0xBF80u : 0u);
  g_qwt[L] = s;
}

// ---- Kernel 2: x NCHW fp32 -> [n][c8][hw][8] bf16, LDS-free --------------
// Lane owns one 16B granule (n,c8,hw): 8 coalesced stride-HW dword streams in,
// 1 KB/wave contiguous uint4 stream out. No LDS, no bank conflicts.
__global__ __launch_bounds__(256) void xform_x(const float* __restrict__ x) {
  int g = blockIdx.x * 256 + threadIdx.x;           // granule id, < 3211264
  int hw = g % HW;
  int tc = g / HW;                                  // n*32 + c8
  int c8 = tc & 31;
  int n  = tc >> 5;
  const float* src = x + (n*IC + c8*8)*HW + hw;
  unsigned int o[4];
  #pragma unroll
  for (int j = 0; j < 4; ++j) {
    unsigned int lo = f32_bf16(src[(2*j+0)*HW]);
    unsigned int hi = f32_bf16(src[(2*j+1)*HW]);
    o[j] = lo | (hi << 16);
  }
  *(uint4*)(&g_xq[g*8]) = *(uint4*)o;
}

// ---- Kernel 3: implicit-GEMM binary conv, 256o x 128m tile ---------------
// 8 waves (4 o-groups x 2 m-groups, 64x64 each), BK=32,
// 2-phase double-buffered LDS with global_load_lds, swizzled ds_read_b128.
__global__ __launch_bounds__(512, 4) void bconv_gemm(float* __restrict__ out) {
  __shared__ __align__(16) unsigned short Wl[2][BO*BK];   // 2 x 16 KB
  __shared__ __align__(16) unsigned short Xl[2][BM*BK];   // 2 x 8 KB
  const int t = threadIdx.x;

  // XCD-aware bijective remap (729 = 8*91 + 1; xcd 0 gets 92 tiles).
  // Consecutive m-tiles share an XCD L2 (im2col halo + the 1.2MB W panel).
  const int orig = blockIdx.x;
  const int xcd  = orig & 7;
  const int idx  = orig >> 3;
  const int bm   = (xcd == 0) ? idx : (92 + (xcd - 1)*91 + idx);
  const int m0   = bm * BM;

  // X staging precompute: thread owns chunk q=t of 512. row i=q>>2, slot cs=q&3.
  // Source chunk is swizzled (cs ^ ((i>>1)&3)) so the LINEAR LDS image holds
  // the swizzled layout (rule: linear dest + pre-swizzled source + swz read).
  int xbase;
  {
    const int i   = t >> 2;                         // m-row 0..127
    const int cs  = t & 3;
    const int csw = cs ^ ((i >> 1) & 3);
    int m  = m0 + i;
    int n  = m / OHW;
    int rm = m - n*OHW;
    int oh = rm / OW;
    int ow = rm - oh*OW;
    xbase = ((n*C8N + csw)*HW + oh*WIDTH + ow) * 8;
  }

  const int lane = t & 63;
  const int wv   = t >> 6;                          // 0..7
  const int col  = lane & 15;
  const int quad = lane >> 4;
  const int wo   = (wv >> 1) * 64;                  // wave o-offset
  const int wm   = (wv & 1) * 64;                   // wave m-offset
  // read-side swizzle: rows are wo/wm + i*16 + col (multiples of 16 + col),
  // so ((row>>1)&3) == ((col>>1)&3) for every fragment -> one constant.
  const int sw   = (quad ^ ((col >> 1) & 3)) * 8;
  int aoff[4], boff[4];
  #pragma unroll
  for (int i = 0; i < 4; ++i) {
    aoff[i] = (wo + i*16 + col)*BK + sw;
    boff[i] = (wm + i*16 + col)*BK + sw;
  }

  auto STAGE = [&](int step, int buf) {
    const unsigned short* ws = g_qwt + step*(BO*BK);
    async_copy16(&ws[t*8],       &Wl[buf][t*8]);         // W: 1024 chunks, linear
    async_copy16(&ws[(t+512)*8], &Wl[buf][(t+512)*8]);
    const int pos = step >> 3;                            // 8 steps per position
    const int kh  = pos / 3;
    const int kw  = pos - kh*3;
    const int xo  = xbase + (((step & 7)*4)*HW + kh*WIDTH + kw)*8;
    async_copy16(&g_xq[xo], &Xl[buf][t*8]);               // X: im2col gather
  };

  f32x4 acc[4][4];
  #pragma unroll
  for (int a = 0; a < 4; ++a)
    #pragma unroll
    for (int b = 0; b < 4; ++b)
      acc[a][b] = (f32x4){0.f, 0.f, 0.f, 0.f};

  // 2-phase pipeline: prologue stage, then per step:
  //   issue next-tile loads FIRST, compute current, one vmcnt(0)+barrier.
  STAGE(0, 0);
  __syncthreads();
  int cur = 0;
  for (int step = 0; step < KSTEPS; ++step) {
    if (step + 1 < KSTEPS) STAGE(step + 1, cur ^ 1);

    bf16x8 av[4], bv[4];
    #pragma unroll
    for (int i = 0; i < 4; ++i) av[i] = *(const bf16x8*)(&Wl[cur][aoff[i]]);
    #pragma unroll
    for (int i = 0; i < 4; ++i) bv[i] = *(const bf16x8*)(&Xl[cur][boff[i]]);

    #pragma unroll
    for (int io = 0; io < 4; ++io)
      #pragma unroll
      for (int im = 0; im < 4; ++im)
        acc[io][im] = __builtin_amdgcn_mfma_f32_16x16x32_bf16(av[io], bv[im], acc[io][im], 0, 0, 0);

    __syncthreads();   // compiler emits s_waitcnt vmcnt(0) lgkmcnt(0) + s_barrier
    cur ^= 1;
  }

  // Epilogue: D col=(lane&15)->m, row=(quad*4+r)->o. out[n][o][oh][ow].
  #pragma unroll
  for (int im = 0; im < 4; ++im) {
    int m  = m0 + wm + im*16 + col;
    int n  = m / OHW;
    int rm = m - n*OHW;
    float* obase = out + n*(OC*OHW) + rm;
    #pragma unroll
    for (int io = 0; io < 4; ++io) {
      int orow = wo + io*16 + quad*4;
      #pragma unroll
      for (int r = 0; r < 4; ++r)
        obase[(orow + r)*OHW] = acc[io][im][r];
    }
  }
}

extern "C" void kernel_launch(void* const* d_in, const int* in_sizes, int n_in,
                              void* d_out, int out_size, void* d_ws, size_t ws_size,
                              hipStream_t stream) {
  const float* x = (const float*)d_in[0];   // [32,256,56,56] fp32
  const float* w = (const float*)d_in[1];   // [256,256,3,3] fp32
  float* out = (float*)d_out;               // [32,256,54,54] fp32

  repack_w<<<dim3((KSTEPS*BO*BK)/256), 256, 0, stream>>>(w);     // 2304 blocks
  xform_x <<<dim3((NB*C8N*HW)/256), 256, 0, stream>>>(x);        // 12544 blocks
  bconv_gemm<<<dim3(MBLOCKS), 512, 0, stream>>>(out);            // 729 blocks
}

// Round 2
// 312.331 us; speedup vs baseline: 1.1511x; 1.0823x over previous
//
#include <hip/hip_runtime.h>
#include <cstdint>

// Problem constants
#define NB 32
#define IC 256
#define OC 256
#define H 56
#define WIDTH 56
#define OH 54
#define OW 54
#define HW (H*WIDTH)          // 3136
#define OHW (OH*OW)           // 2916
#define KTOT 2304             // 9 * 256, k = (kh*3+kw)*256 + c
#define M_TOT (NB*OHW)        // 93312
#define C8N (IC/8)            // 32 chunks of 8 channels

// GEMM tiling
#define BM 128                // spatial tile
#define BO 256                // out-channel tile (= all of OC: X staged once)
#define BK 32
#define KSTEPS (KTOT/BK)      // 72
#define MBLOCKS (M_TOT/BM)    // 729

// weights pre-tiled as per-K-step LDS images WITH chunk swizzle:
// g_qwt[step][r][cs][b] = sign(W[o=r][k = step*32 + (cs ^ ((r>>1)&3))*8 + b])
__device__ __align__(16) unsigned short g_qwt[KSTEPS*BO*BK];
// x as [n][c8][hw][8] bf16 (16B granule = 8 consecutive channels at one pixel)
__device__ __align__(16) unsigned short g_xq[NB*C8N*HW*8];

typedef __bf16 bf16x8 __attribute__((ext_vector_type(8)));
typedef float  f32x4  __attribute__((ext_vector_type(4)));

typedef __attribute__((address_space(1))) const unsigned int gas_u32;
typedef __attribute__((address_space(3))) unsigned int las_u32;
__device__ __forceinline__ void async_copy16(const void* g, void* l) {
  // global -> LDS direct copy, 16 B per lane; LDS dst = wave-uniform base + lane*16
  __builtin_amdgcn_global_load_lds((gas_u32*)g, (las_u32*)l, 16, 0, 0);
}

__device__ inline unsigned short f32_bf16(float f) {
  union { float f; unsigned int u; } v; v.f = f;
  unsigned int u = v.u;
  return (unsigned short)((u + 0x7FFFu + ((u >> 16) & 1u)) >> 16);  // RNE
}

// Counted vmcnt wait (T4): N outstanding VMEM ops may remain in flight.
#define WAITV(N) asm volatile("s_waitcnt vmcnt(" #N ")" ::: "memory")
// Raw barrier (no implicit vmcnt(0) drain, unlike __syncthreads()).
#define BARRIER() do { \
  __builtin_amdgcn_sched_barrier(0); \
  __builtin_amdgcn_s_barrier(); \
  __builtin_amdgcn_sched_barrier(0); \
} while (0)

// ---- Kernel 1: binarize + pre-tile weights (swizzled LDS image) ----------
__global__ __launch_bounds__(256) void repack_w(const float* __restrict__ w) {
  int L = blockIdx.x * 256 + threadIdx.x;           // < 589824
  int step = L >> 13;                               // /8192 (256 rows * 32 k)
  int r    = (L >> 5) & 255;
  int kc   = L & 31;
  int cs   = kc >> 3;                               // chunk slot 0..3
  int b    = kc & 7;
  int csrc = cs ^ ((r >> 1) & 3);                   // bank-conflict swizzle
  int k    = step*BK + csrc*8 + b;
  int pos  = k >> 8;                                // kh*3+kw
  int c    = k & 255;
  float v = w[r*2304 + c*9 + pos];
  unsigned short s = (v > 0.f) ? 0x3F80u : ((v < 0.f) ? 0xBF80u : 0u);
  g_qwt[L] = s;
}

// ---- Kernel 2: x NCHW fp32 -> [n][c8][hw][8] bf16, LDS-free --------------
__global__ __launch_bounds__(256) void xform_x(const float* __restrict__ x) {
  int g = blockIdx.x * 256 + threadIdx.x;           // granule id, < 3211264
  int hw = g % HW;
  int tc = g / HW;                                  // n*32 + c8
  int c8 = tc & 31;
  int n  = tc >> 5;
  const float* src = x + (n*IC + c8*8)*HW + hw;
  unsigned int o[4];
  #pragma unroll
  for (int j = 0; j < 4; ++j) {
    unsigned int lo = f32_bf16(src[(2*j+0)*HW]);
    unsigned int hi = f32_bf16(src[(2*j+1)*HW]);
    o[j] = lo | (hi << 16);
  }
  *(uint4*)(&g_xq[g*8]) = *(uint4*)o;
}

// ---- Kernel 3: implicit-GEMM binary conv, 256o x 128m tile ---------------
// 8 waves (4 o-groups x 2 m-groups, 64x64 each), BK=32.
// 3-deep circular LDS pipeline with counted vmcnt (never 0 in main loop):
//   iter s: [bar] STAGE(s+2) ; vmcnt(6) ; [bar] ; ds_read+MFMA(buf s%3)
// The waited-on tile was staged TWO compute phases ago -> latency covered.
__global__ __launch_bounds__(512, 4) void bconv_gemm(float* __restrict__ out) {
  __shared__ __align__(16) unsigned short Wl[3][BO*BK];   // 3 x 16 KB
  __shared__ __align__(16) unsigned short Xl[3][BM*BK];   // 3 x  8 KB  (72 KB total)
  const int t = threadIdx.x;

  // XCD-aware bijective remap (729 = 8*91 + 1; xcd 0 gets 92 tiles).
  const int orig = blockIdx.x;
  const int xcd  = orig & 7;
  const int idx  = orig >> 3;
  const int bm   = (xcd == 0) ? idx : (92 + (xcd - 1)*91 + idx);
  const int m0   = bm * BM;

  // X staging precompute: thread owns chunk q=t of 512. row i=q>>2, slot cs=q&3.
  // Source chunk is swizzled (cs ^ ((i>>1)&3)) -> linear LDS dest holds the
  // swizzled layout (rule: linear dest + pre-swizzled source + swizzled read).
  int xbase;
  {
    const int i   = t >> 2;                         // m-row 0..127
    const int cs  = t & 3;
    const int csw = cs ^ ((i >> 1) & 3);
    int m  = m0 + i;
    int n  = m / OHW;
    int rm = m - n*OHW;
    int oh = rm / OW;
    int ow = rm - oh*OW;
    xbase = ((n*C8N + csw)*HW + oh*WIDTH + ow) * 8;
  }

  const int lane = t & 63;
  const int wv   = t >> 6;                          // 0..7
  const int col  = lane & 15;
  const int quad = lane >> 4;
  const int wo   = (wv >> 1) * 64;                  // wave o-offset (0,64,128,192)
  const int wm   = (wv & 1) * 64;                   // wave m-offset (0,64)
  // read-side swizzle: rows are (multiple of 16) + col -> ((row>>1)&3)==((col>>1)&3)
  const int sw   = (quad ^ ((col >> 1) & 3)) * 8;
  int aoff[4], boff[4];
  #pragma unroll
  for (int i = 0; i < 4; ++i) {
    aoff[i] = (wo + i*16 + col)*BK + sw;
    boff[i] = (wm + i*16 + col)*BK + sw;
  }

  auto STAGE = [&](int step, int buf) {
    const unsigned short* ws = g_qwt + step*(BO*BK);
    async_copy16(&ws[t*8],       &Wl[buf][t*8]);         // W: 1024 chunks, linear
    async_copy16(&ws[(t+512)*8], &Wl[buf][(t+512)*8]);
    const int pos = step >> 3;                            // 8 steps per position
    const int kh  = pos / 3;
    const int kw  = pos - kh*3;
    const int xo  = xbase + (((step & 7)*4)*HW + kh*WIDTH + kw)*8;
    async_copy16(&g_xq[xo], &Xl[buf][t*8]);               // X: im2col gather
  };

  f32x4 acc[4][4];
  #pragma unroll
  for (int a = 0; a < 4; ++a)
    #pragma unroll
    for (int b = 0; b < 4; ++b)
      acc[a][b] = (f32x4){0.f, 0.f, 0.f, 0.f};

  auto COMPUTE = [&](const unsigned short* Wb, const unsigned short* Xb) {
    bf16x8 av[4], bv[4];
    #pragma unroll
    for (int i = 0; i < 4; ++i) av[i] = *(const bf16x8*)(&Wb[aoff[i]]);
    #pragma unroll
    for (int i = 0; i < 4; ++i) bv[i] = *(const bf16x8*)(&Xb[boff[i]]);
    __builtin_amdgcn_s_setprio(1);
    #pragma unroll
    for (int io = 0; io < 4; ++io)
      #pragma unroll
      for (int im = 0; im < 4; ++im)
        acc[io][im] = __builtin_amdgcn_mfma_f32_16x16x32_bf16(av[io], bv[im], acc[io][im], 0, 0, 0);
    __builtin_amdgcn_s_setprio(0);
  };

  // Prologue: fill the 3-deep pipe (9 outstanding VMEM ops per thread).
  STAGE(0, 0);
  STAGE(1, 1);
  STAGE(2, 2);
  WAITV(6);            // tile 0 landed (ours)
  BARRIER();           // tile 0 landed (everyone's)
  COMPUTE(Wl[0], Xl[0]);                 // tile 0

  // Main loop: tiles 1..69, unrolled x3 for compile-time buffer indices.
  #pragma unroll 1
  for (int s = 1; s < 68; s += 3) {
    BARRIER();                            // all waves done reading buf0
    STAGE(s + 2, 0);
    WAITV(6);
    BARRIER();
    COMPUTE(Wl[1], Xl[1]);                // tile s

    BARRIER();
    STAGE(s + 3, 1);
    WAITV(6);
    BARRIER();
    COMPUTE(Wl[2], Xl[2]);                // tile s+1

    BARRIER();
    STAGE(s + 4, 2);
    WAITV(6);
    BARRIER();
    COMPUTE(Wl[0], Xl[0]);                // tile s+2
  }

  // Tail: tiles 70 (buf1) and 71 (buf2); drain counted waits.
  BARRIER();
  WAITV(3);
  BARRIER();
  COMPUTE(Wl[1], Xl[1]);                  // tile 70
  BARRIER();
  WAITV(0);
  BARRIER();
  COMPUTE(Wl[2], Xl[2]);                  // tile 71

  // Epilogue: D col=(lane&15)->m, row=(quad*4+r)->o. out[n][o][oh][ow].
  #pragma unroll
  for (int im = 0; im < 4; ++im) {
    int m  = m0 + wm + im*16 + col;
    int n  = m / OHW;
    int rm = m - n*OHW;
    float* obase = out + n*(OC*OHW) + rm;
    #pragma unroll
    for (int io = 0; io < 4; ++io) {
      int orow = wo + io*16 + quad*4;
      #pragma unroll
      for (int r = 0; r < 4; ++r)
        obase[(orow + r)*OHW] = acc[io][im][r];
    }
  }
}

extern "C" void kernel_launch(void* const* d_in, const int* in_sizes, int n_in,
                              void* d_out, int out_size, void* d_ws, size_t ws_size,
                              hipStream_t stream) {
  const float* x = (const float*)d_in[0];   // [32,256,56,56] fp32
  const float* w = (const float*)d_in[1];   // [256,256,3,3] fp32
  float* out = (float*)d_out;               // [32,256,54,54] fp32

  repack_w<<<dim3((KSTEPS*BO*BK)/256), 256, 0, stream>>>(w);     // 2304 blocks
  xform_x <<<dim3((NB*C8N*HW)/256), 256, 0, stream>>>(x);        // 12544 blocks
  bconv_gemm<<<dim3(MBLOCKS), 512, 0, stream>>>(out);            // 729 blocks
}